// Round 6
// baseline (127.972 us; speedup 1.0000x reference)
//
#include <hip/hip_runtime.h>
#include <stdint.h>

#define HW   4096      // 64*64 spatial per batch
#define NEMB 1024

typedef float f2 __attribute__((ext_vector_type(2)));
typedef float f4 __attribute__((ext_vector_type(4)));

// packed fp32 FMA: lo/hi acc chains stay independent + sequential (bit-exact).
// PKL: b-operand broadcasts LO word of E-pair; PKH: broadcasts HI word.
#define PKL(A, Z, E) asm("v_pk_fma_f32 %0, %1, %2, %0 op_sel_hi:[1,0,1]" : "+v"(A) : "v"(Z), "v"(E))
#define PKH(A, Z, E) asm("v_pk_fma_f32 %0, %1, %2, %0 op_sel:[0,1,0]"   : "+v"(A) : "v"(Z), "v"(E))

// direct global->LDS DMA, 16B per lane (linear dest = wave base + lane*16)
__device__ __forceinline__ void gload_lds16(const float* g, float* l) {
    __builtin_amdgcn_global_load_lds(
        (const __attribute__((address_space(1))) void*)(uintptr_t)g,
        (__attribute__((address_space(3))) void*)(uintptr_t)l, 16, 0, 0);
}

// ---------------- init: zero counts + errsum, precompute enorm ----------------
// numpy pairwise-8 accumulator order (verified bit-exact r1..r5).
__global__ __launch_bounds__(128) void vq_init(const float* __restrict__ emb,
                                               unsigned int* __restrict__ counts,
                                               float* __restrict__ errsum,
                                               float* __restrict__ enorm) {
    const int k = blockIdx.x * 128 + threadIdx.x;
    counts[k] = 0u;
    if (k == 0) *errsum = 0.0f;
    const float* e = emb + k * 64;
    float a[8] = {0,0,0,0,0,0,0,0};
    #pragma unroll
    for (int c = 0; c < 16; ++c) {
        f4 v = *(const f4*)(e + c * 4);
        a[(4*c+0) & 7] += v.x * v.x;
        a[(4*c+1) & 7] += v.y * v.y;
        a[(4*c+2) & 7] += v.z * v.z;
        a[(4*c+3) & 7] += v.w * v.w;
    }
    enorm[k] = ((a[0]+a[1]) + (a[2]+a[3])) + ((a[4]+a[5]) + (a[6]+a[7]));
}

// ---------------- main ----------------
// grid 256 x 512 (1 block/CU). Block: 256 samples, 4 k-tiles of 256 embeddings.
// Thread (ng = t>>5, kl = t&31): 16 samples x 8 embeddings.
__global__ __launch_bounds__(512, 2)
void vq_main(const float* __restrict__ z, const float* __restrict__ emb,
             const float* __restrict__ enorm,
             float* __restrict__ out, unsigned int* __restrict__ counts,
             float* __restrict__ errsum)
{
    __shared__ __attribute__((aligned(16))) float zt[64 * 256];  // [d][x], linear
    __shared__ __attribute__((aligned(16))) float et[256 * 64];  // row r: slot s = chunk s^((r>>3)&15)
    __shared__ __attribute__((aligned(16))) float en_all[NEMB];
    __shared__ float znorm_s[256];
    __shared__ float md_sh[256];
    __shared__ int   idx_sh[256];

    const int t   = threadIdx.x;
    const int n0  = blockIdx.x * 256;
    const int bb  = n0 >> 12;        // batch index (256 | 4096)
    const int hw0 = n0 & 4095;
    const float* zb = z + bb * (64 * HW) + hw0;   // + d*HW + x

    // ---- issue et tile 0 DMA (pre-swizzled source, linear dest) ----
    #pragma unroll
    for (int it = 0; it < 8; ++it) {
        const int p  = it * 512 + t;                 // float4 position 0..4095
        const int r  = p >> 4;                       // row 0..255
        const int dc = (p & 15) ^ ((r >> 3) & 15);   // inverse swizzle on SOURCE
        gload_lds16(emb + r * 64 + dc * 4, et + p * 4);
    }
    // ---- issue zt DMA: global [d][x] rows -> LDS [d][x] linear ----
    #pragma unroll
    for (int it = 0; it < 8; ++it) {
        const int p = it * 512 + t;                  // float4 position 0..4095
        const int d = p >> 6;
        const int x = (p & 63) * 4;
        gload_lds16(zb + d * HW + x, zt + p * 4);
    }
    // ---- stage all 1024 enorms ----
    *(f2*)&en_all[t * 2] = *(const f2*)&enorm[t * 2];
    __syncthreads();   // DMA drained: zt + et0 + en_all visible

    // ---- znorm, numpy pairwise-8 order ----
    if (t < 256) {
        float a[8] = {0,0,0,0,0,0,0,0};
        #pragma unroll
        for (int d = 0; d < 64; ++d) {
            float v = zt[d * 256 + t];
            a[d & 7] += v * v;
        }
        znorm_s[t] = ((a[0]+a[1]) + (a[2]+a[3])) + ((a[4]+a[5]) + (a[6]+a[7]));
    }
    __syncthreads();

    const int kl = t & 31;   // emb-lane (0..31): rows kl*8..kl*8+7 of the 256-tile
    const int ng = t >> 5;   // sample-group (0..15): samples ng*16..ng*16+15
    const int klm = kl & 15; // et swizzle factor for rows kl*8+j (j<8)
    const float* ep = et + kl * 512;        // row kl*8+j at +j*64
    const float* zp = zt + ng * 16;         // + d*256

    float mval[16];
    int   midx[16];
    #pragma unroll
    for (int i = 0; i < 16; ++i) { mval[i] = __builtin_inff(); midx[i] = 0; }

    #pragma unroll 1
    for (int kt = 0; kt < 4; ++kt) {
        const int kbase = kt << 8;

        float en[8];
        {
            f4 ea = *(const f4*)&en_all[kbase + kl * 8];
            f4 eb = *(const f4*)&en_all[kbase + kl * 8 + 4];
            en[0]=ea.x; en[1]=ea.y; en[2]=ea.z; en[3]=ea.w;
            en[4]=eb.x; en[5]=eb.y; en[6]=eb.z; en[7]=eb.w;
        }

        f2 acc[8][8];   // [sample-pair][emb j]
        #pragma unroll
        for (int sp = 0; sp < 8; ++sp)
            #pragma unroll
            for (int j = 0; j < 8; ++j) acc[sp][j] = (f2)(0.0f);

        // dot: packed over sample-pairs; each acc half is the ascending-d
        // sequential IEEE-FMA chain (bit-exact vs numpy/BLAS reference).
        #pragma unroll 2
        for (int dc = 0; dc < 16; ++dc) {
            const int eo = ((dc ^ klm) << 2);
            f4 ef[8];
            #pragma unroll
            for (int j = 0; j < 8; ++j) ef[j] = *(const f4*)(ep + j * 64 + eo);
            #pragma unroll
            for (int ds = 0; ds < 4; ++ds) {
                const float* zr = zp + (dc * 4 + ds) * 256;
                f4 q0 = *(const f4*)(zr + 0);
                f4 q1 = *(const f4*)(zr + 4);
                f4 q2 = *(const f4*)(zr + 8);
                f4 q3 = *(const f4*)(zr + 12);
                f2 zp0 = __builtin_shufflevector(q0, q0, 0, 1);
                f2 zp1 = __builtin_shufflevector(q0, q0, 2, 3);
                f2 zp2 = __builtin_shufflevector(q1, q1, 0, 1);
                f2 zp3 = __builtin_shufflevector(q1, q1, 2, 3);
                f2 zp4 = __builtin_shufflevector(q2, q2, 0, 1);
                f2 zp5 = __builtin_shufflevector(q2, q2, 2, 3);
                f2 zp6 = __builtin_shufflevector(q3, q3, 0, 1);
                f2 zp7 = __builtin_shufflevector(q3, q3, 2, 3);
                #pragma unroll
                for (int j = 0; j < 8; ++j) {
                    f2 e2 = (ds < 2) ? __builtin_shufflevector(ef[j], ef[j], 0, 1)
                                     : __builtin_shufflevector(ef[j], ef[j], 2, 3);
                    if ((ds & 1) == 0) {
                        PKL(acc[0][j], zp0, e2); PKL(acc[1][j], zp1, e2);
                        PKL(acc[2][j], zp2, e2); PKL(acc[3][j], zp3, e2);
                        PKL(acc[4][j], zp4, e2); PKL(acc[5][j], zp5, e2);
                        PKL(acc[6][j], zp6, e2); PKL(acc[7][j], zp7, e2);
                    } else {
                        PKH(acc[0][j], zp0, e2); PKH(acc[1][j], zp1, e2);
                        PKH(acc[2][j], zp2, e2); PKH(acc[3][j], zp3, e2);
                        PKH(acc[4][j], zp4, e2); PKH(acc[5][j], zp5, e2);
                        PKH(acc[6][j], zp6, e2); PKH(acc[7][j], zp7, e2);
                    }
                }
            }
        }

        __syncthreads();   // all waves done READING et[kt]
        if (kt < 3) {      // issue et[kt+1] DMA; latency hides under argmin tail
            #pragma unroll
            for (int it = 0; it < 8; ++it) {
                const int p  = it * 512 + t;
                const int r  = p >> 4;
                const int dc = (p & 15) ^ ((r >> 3) & 15);
                gload_lds16(emb + (kbase + 256 + r) * 64 + dc * 4, et + p * 4);
            }
        }

        // distances + running argmin (ascending k, strict < => first-index tie-break)
        {
            f4 znv0 = *(const f4*)&znorm_s[ng * 16 + 0];
            f4 znv1 = *(const f4*)&znorm_s[ng * 16 + 4];
            f4 znv2 = *(const f4*)&znorm_s[ng * 16 + 8];
            f4 znv3 = *(const f4*)&znorm_s[ng * 16 + 12];
            float zn[16] = {znv0.x,znv0.y,znv0.z,znv0.w, znv1.x,znv1.y,znv1.z,znv1.w,
                            znv2.x,znv2.y,znv2.z,znv2.w, znv3.x,znv3.y,znv3.z,znv3.w};
            #pragma unroll
            for (int j = 0; j < 8; ++j) {
                const int kg = kbase + kl * 8 + j;
                #pragma unroll
                for (int sp = 0; sp < 8; ++sp) {
                    {
                        const float tt   = zn[2*sp] + en[j];
                        const float dist = fmaf(-2.0f, acc[sp][j][0], tt);
                        if (dist < mval[2*sp]) { mval[2*sp] = dist; midx[2*sp] = kg; }
                    }
                    {
                        const float tt   = zn[2*sp+1] + en[j];
                        const float dist = fmaf(-2.0f, acc[sp][j][1], tt);
                        if (dist < mval[2*sp+1]) { mval[2*sp+1] = dist; midx[2*sp+1] = kg; }
                    }
                }
            }
        }

        __syncthreads();   // drains vmcnt -> et[kt+1] ready
    }

    // ---- cross-lane argmin over 32 k-lanes (tie-break: smaller k) ----
    #pragma unroll
    for (int i = 0; i < 16; ++i) {
        float m = mval[i]; int id = midx[i];
        #pragma unroll
        for (int mask = 1; mask <= 16; mask <<= 1) {
            float m2 = __shfl_xor(m, mask, 64);
            int   i2 = __shfl_xor(id, mask, 64);
            if (m2 < m || (m2 == m && i2 < id)) { m = m2; id = i2; }
        }
        if (kl == 0) { md_sh[ng*16 + i] = m; idx_sh[ng*16 + i] = id; }
    }
    __syncthreads();

    // ---- histogram + error sum (min distance == ||z-e||^2) ----
    if (t < 256) atomicAdd(&counts[idx_sh[t]], 1u);
    if (t < 64) {
        float s = (md_sh[t] + md_sh[t + 64]) + (md_sh[t + 128] + md_sh[t + 192]);
        #pragma unroll
        for (int off = 32; off >= 1; off >>= 1) s += __shfl_down(s, off, 64);
        if (t == 0) atomicAdd(errsum, s);
    }

    // ---- epilogue: out = z + (q - z), exact ref rounding ----
    {
        const int x  = t & 255;
        const int cg = t >> 8;     // 0/1 -> channels cg*32..cg*32+31
        const int idx = idx_sh[x];
        const float* er = emb + idx * 64;
        float* ob = out + bb * (64 * HW) + hw0 + x;
        #pragma unroll
        for (int cq = 0; cq < 8; ++cq) {
            const int c = cg * 32 + cq * 4;
            f4 e4 = *(const f4*)&er[c];
            float z0 = zt[(c+0) * 256 + x];
            float z1 = zt[(c+1) * 256 + x];
            float z2 = zt[(c+2) * 256 + x];
            float z3 = zt[(c+3) * 256 + x];
            ob[(c+0) * HW] = z0 + (e4.x - z0);
            ob[(c+1) * HW] = z1 + (e4.y - z1);
            ob[(c+2) * HW] = z2 + (e4.z - z2);
            ob[(c+3) * HW] = z3 + (e4.w - z3);
        }
    }
}

// ---------------- finalize: scalars ----------------
__global__ __launch_bounds__(256) void vq_fin(const unsigned int* __restrict__ counts,
                                              const float* __restrict__ errsum,
                                              float* __restrict__ scal)
{
    __shared__ float part[4];
    const int t = threadIdx.x;
    float s = 0.0f;
    for (int k = t; k < NEMB; k += 256) {
        float p = (float)counts[k] * (1.0f / 65536.0f);
        s += p * logf(p + 1e-10f);
    }
    #pragma unroll
    for (int off = 32; off >= 1; off >>= 1) s += __shfl_down(s, off, 64);
    if ((t & 63) == 0) part[t >> 6] = s;
    __syncthreads();
    if (t == 0) {
        float tot = (part[0] + part[1]) + (part[2] + part[3]);
        float es  = *errsum;
        scal[0] = 1.25f * (es * (1.0f / 4194304.0f));  // loss = 1.25 * mse
        scal[1] = expf(-tot);                          // perplexity
        scal[2] = es * (1.0f / 65536.0f);              // avg_error
    }
}

extern "C" void kernel_launch(void* const* d_in, const int* in_sizes, int n_in,
                              void* d_out, int out_size, void* d_ws, size_t ws_size,
                              hipStream_t stream) {
    const float* z   = (const float*)d_in[0];
    const float* emb = (const float*)d_in[1];
    float* out = (float*)d_out;
    unsigned int* counts = (unsigned int*)d_ws;
    float* errsum = (float*)((char*)d_ws + 4096);
    float* enorm  = (float*)((char*)d_ws + 8192);

    vq_init<<<8, 128, 0, stream>>>(emb, counts, errsum, enorm);
    vq_main<<<256, 512, 0, stream>>>(z, emb, enorm, out, counts, errsum);
    vq_fin<<<1, 256, 0, stream>>>(counts, errsum, out + 4194304);
}